// Round 2
// baseline (505.164 us; speedup 1.0000x reference)
//
#include <hip/hip_runtime.h>
#include <math.h>

#define BATCH   4096
#define TSTEPS  512
#define FDIM    32

// ds_swizzle with compile-time pattern (BitMode: offset = (xor<<10)|(or<<5)|and)
template<int PAT>
__device__ __forceinline__ float swzf(float v) {
    return __int_as_float(__builtin_amdgcn_ds_swizzle(__float_as_int(v), PAT));
}

__device__ __forceinline__ float fast_rcp(float x) { return __builtin_amdgcn_rcpf(x); }

__device__ __forceinline__ float fast_tanh(float x) {
    // tanh(x) = 1 - 2/(e^{2x}+1); e->inf => 1, e->0 => -1
    float e = __expf(2.0f * x);
    return 1.0f - 2.0f * fast_rcp(e + 1.0f);
}

__device__ __forceinline__ float sigmoidf_(float x) {
    return fast_rcp(1.0f + __expf(-x));
}

struct LState {
    float h0, h1, h2, h3, h4, h5, h6, h7, c;
};

__device__ __forceinline__ void ldx(float4 xv[8], const float4* __restrict__ p) {
#pragma unroll
    for (int i = 0; i < 8; ++i) xv[i] = p[i];
}

// One LSTM timestep. Lane layout: l = (r<<4)|(gp<<3)|u.
// gp=0 lane owns gates {i_u, f_u}; gp=1 lane owns {g_u, o_u}. All over full K=32.
__device__ __forceinline__ void lstep(const float4 xv[8],
                                      const float kc0[FDIM], const float kc1[FDIM],
                                      const float rc0[8], const float rc1[8],
                                      float ba, float bb, bool gp1, LState& s)
{
    float a0 = ba, a1 = 0.f, a2 = 0.f, a3 = 0.f;
    float b0 = bb, b1 = 0.f, b2 = 0.f, b3 = 0.f;
#pragma unroll
    for (int f4 = 0; f4 < 8; ++f4) {
        float4 xw = xv[f4];
        a0 = fmaf(xw.x, kc0[4 * f4 + 0], a0);
        a1 = fmaf(xw.y, kc0[4 * f4 + 1], a1);
        a2 = fmaf(xw.z, kc0[4 * f4 + 2], a2);
        a3 = fmaf(xw.w, kc0[4 * f4 + 3], a3);
        b0 = fmaf(xw.x, kc1[4 * f4 + 0], b0);
        b1 = fmaf(xw.y, kc1[4 * f4 + 1], b1);
        b2 = fmaf(xw.z, kc1[4 * f4 + 2], b2);
        b3 = fmaf(xw.w, kc1[4 * f4 + 3], b3);
    }
    a0 = fmaf(s.h0, rc0[0], a0); a1 = fmaf(s.h1, rc0[1], a1);
    a2 = fmaf(s.h2, rc0[2], a2); a3 = fmaf(s.h3, rc0[3], a3);
    a0 = fmaf(s.h4, rc0[4], a0); a1 = fmaf(s.h5, rc0[5], a1);
    a2 = fmaf(s.h6, rc0[6], a2); a3 = fmaf(s.h7, rc0[7], a3);
    b0 = fmaf(s.h0, rc1[0], b0); b1 = fmaf(s.h1, rc1[1], b1);
    b2 = fmaf(s.h2, rc1[2], b2); b3 = fmaf(s.h3, rc1[3], b3);
    b0 = fmaf(s.h4, rc1[4], b0); b1 = fmaf(s.h5, rc1[5], b1);
    b2 = fmaf(s.h6, rc1[6], b2); b3 = fmaf(s.h7, rc1[7], b3);
    float za = (a0 + a1) + (a2 + a3);
    float zb = (b0 + b1) + (b2 + b3);

    // gp=0: va=i (relu), vb=f (relu);  gp=1: va=g (tanh), vb=o (relu)
    float va = gp1 ? fast_tanh(za) : fmaxf(za, 0.f);
    float vb = fmaxf(zb, 0.f);

    // partner exchange across the gp bit (xor 8, stays in the 16-lane row group)
    float pa = swzf<0x201F>(va);
    float pb = swzf<0x201F>(vb);
    float gi = gp1 ? pa : va;
    float gf = gp1 ? pb : vb;
    float gg = gp1 ? va : pa;
    float go = gp1 ? vb : pb;

    s.c = fmaf(gf, s.c, gi * gg);
    float hn = go * fast_tanh(s.c);

    // broadcast h_u from lane (l&0x10)|hu (same row group, gp=0 replica)
    s.h0 = swzf<0x010>(hn); s.h1 = swzf<0x030>(hn);
    s.h2 = swzf<0x050>(hn); s.h3 = swzf<0x070>(hn);
    s.h4 = swzf<0x090>(hn); s.h5 = swzf<0x0B0>(hn);
    s.h6 = swzf<0x0D0>(hn); s.h7 = swzf<0x0F0>(hn);
}

__global__ __launch_bounds__(256, 1)
void lstm_fused(const float* __restrict__ x,
                const float* __restrict__ kern,
                const float* __restrict__ rk,
                const float* __restrict__ bias,
                const float* __restrict__ w1,
                const float* __restrict__ b1,
                const float* __restrict__ w2,
                const float* __restrict__ b2,
                float* __restrict__ out)
{
    const int tid = threadIdx.x;
    const int wv  = tid >> 6;
    const int l   = tid & 63;
    const int u   = l & 7;
    const int gp  = (l >> 3) & 1;
    const int rl  = l >> 4;                    // 0..3
    const int row = blockIdx.x * 16 + wv * 4 + rl;
    const bool gp1 = (gp != 0);
    const int g0 = gp ? 16 + u : u;            // gate column for va
    const int g1 = gp ? 24 + u : 8 + u;        // gate column for vb

    // --- weights resident in registers ---
    float kc0[FDIM], kc1[FDIM];
#pragma unroll
    for (int f = 0; f < FDIM; ++f) {
        kc0[f] = kern[f * 32 + g0];
        kc1[f] = kern[f * 32 + g1];
    }
    float rc0[8], rc1[8];
#pragma unroll
    for (int i = 0; i < 8; ++i) {
        rc0[i] = rk[i * 32 + g0];
        rc1[i] = rk[i * 32 + g1];
    }
    const float ba = bias[g0], bb = bias[g1];

    const float4* xr = (const float4*)(x + (size_t)row * (TSTEPS * FDIM));  // +t*8 per step

    LState s = {0.f, 0.f, 0.f, 0.f, 0.f, 0.f, 0.f, 0.f, 0.f};

    // triple-buffered direct global->VGPR prefetch (2-step latency cover)
    float4 X0[8], X1[8], X2[8];
    ldx(X0, xr + 0 * 8);
    ldx(X1, xr + 1 * 8);
    ldx(X2, xr + 2 * 8);

    for (int tb = 0; tb < 510; tb += 3) {
        lstep(X0, kc0, kc1, rc0, rc1, ba, bb, gp1, s);
        ldx(X0, xr + (size_t)min(tb + 3, TSTEPS - 1) * 8);
        lstep(X1, kc0, kc1, rc0, rc1, ba, bb, gp1, s);
        ldx(X1, xr + (size_t)min(tb + 4, TSTEPS - 1) * 8);
        lstep(X2, kc0, kc1, rc0, rc1, ba, bb, gp1, s);
        ldx(X2, xr + (size_t)min(tb + 5, TSTEPS - 1) * 8);
    }
    lstep(X0, kc0, kc1, rc0, rc1, ba, bb, gp1, s);   // t = 510
    lstep(X1, kc0, kc1, rc0, rc1, ba, bb, gp1, s);   // t = 511

    // --- MLP head: m = relu(h @ w1 + b1) [64]; out = sigmoid(m @ w2 + b2) [4] ---
    const int q = l & 15;          // (gp<<3)|u : 16 lanes per row
    const float hh[8] = {s.h0, s.h1, s.h2, s.h3, s.h4, s.h5, s.h6, s.h7};
    float m[4];
#pragma unroll
    for (int k = 0; k < 4; ++k) {
        const int cc = q * 4 + k;
        float mm = b1[cc];
#pragma unroll
        for (int hu = 0; hu < 8; ++hu) mm = fmaf(hh[hu], w1[hu * 64 + cc], mm);
        m[k] = fmaxf(mm, 0.f);
    }
    float s0 = 0.f, s1 = 0.f, s2 = 0.f, s3 = 0.f;
#pragma unroll
    for (int k = 0; k < 4; ++k) {
        const int cc = q * 4 + k;
        s0 = fmaf(m[k], w2[cc * 4 + 0], s0);
        s1 = fmaf(m[k], w2[cc * 4 + 1], s1);
        s2 = fmaf(m[k], w2[cc * 4 + 2], s2);
        s3 = fmaf(m[k], w2[cc * 4 + 3], s3);
    }
    // butterfly reduce over the 16-lane row group (xor 1,2,4,8)
    s0 += swzf<0x041F>(s0); s1 += swzf<0x041F>(s1); s2 += swzf<0x041F>(s2); s3 += swzf<0x041F>(s3);
    s0 += swzf<0x081F>(s0); s1 += swzf<0x081F>(s1); s2 += swzf<0x081F>(s2); s3 += swzf<0x081F>(s3);
    s0 += swzf<0x101F>(s0); s1 += swzf<0x101F>(s1); s2 += swzf<0x101F>(s2); s3 += swzf<0x101F>(s3);
    s0 += swzf<0x201F>(s0); s1 += swzf<0x201F>(s1); s2 += swzf<0x201F>(s2); s3 += swzf<0x201F>(s3);

    if (q == 0) {
        float4 o;
        o.x = sigmoidf_(s0 + b2[0]);
        o.y = sigmoidf_(s1 + b2[1]);
        o.z = sigmoidf_(s2 + b2[2]);
        o.w = sigmoidf_(s3 + b2[3]);
        *(float4*)&out[(size_t)row * 4] = o;
    }
}

extern "C" void kernel_launch(void* const* d_in, const int* in_sizes, int n_in,
                              void* d_out, int out_size, void* d_ws, size_t ws_size,
                              hipStream_t stream)
{
    const float* x    = (const float*)d_in[0];
    const float* kern = (const float*)d_in[1];
    const float* rk   = (const float*)d_in[2];
    const float* bias = (const float*)d_in[3];
    const float* w1   = (const float*)d_in[4];
    const float* b1   = (const float*)d_in[5];
    const float* w2   = (const float*)d_in[6];
    const float* b2   = (const float*)d_in[7];

    dim3 grid(BATCH / 16);   // 256 blocks = 1 per CU; 4 waves/block, 4 rows/wave
    dim3 block(256);
    lstm_fused<<<grid, block, 0, stream>>>(x, kern, rk, bias, w1, b1, w2, b2, (float*)d_out);
}

// Round 4
// 495.467 us; speedup vs baseline: 1.0196x; 1.0196x over previous
//
#include <hip/hip_runtime.h>
#include <hip/hip_bf16.h>
#include <math.h>

#define TSTEPS 512
#define FDIM   32

typedef __attribute__((ext_vector_type(8))) short bf16x8;
typedef __attribute__((ext_vector_type(4))) float f32x4;

// ds_swizzle, BitMode: offset = (xor<<10)|(or<<5)|and
template<int PAT>
__device__ __forceinline__ float swzf(float v) {
    return __int_as_float(__builtin_amdgcn_ds_swizzle(__float_as_int(v), PAT));
}

// value from lane^32 (cross 32-half). Orientation-robust: exactly one of r[0]/r[1]
// equals own value; the other is the partner's.
__device__ __forceinline__ float crossf(float v) {
#if __has_builtin(__builtin_amdgcn_permlane32_swap)
    unsigned u = __float_as_uint(v);
    auto r = __builtin_amdgcn_permlane32_swap(u, u, false, false);
    unsigned c = (r[0] == u) ? r[1] : r[0];
    return __uint_as_float(c);
#else
    return __shfl_xor(v, 32, 64);
#endif
}

__device__ __forceinline__ float fast_rcp(float x) { return __builtin_amdgcn_rcpf(x); }
__device__ __forceinline__ float fast_tanh(float x) {
    float e = __expf(2.0f * x);
    return 1.0f - 2.0f * fast_rcp(e + 1.0f);
}
__device__ __forceinline__ float sigmoidf_(float x) { return fast_rcp(1.0f + __expf(-x)); }

__device__ __forceinline__ unsigned short f2bfu(float f) {
    __hip_bfloat16 h = __float2bfloat16(f);
    unsigned short u; __builtin_memcpy(&u, &h, 2); return u;
}
__device__ __forceinline__ unsigned pk2(float a, float b) {
    __hip_bfloat162 t = __float22bfloat162_rn(float2{a, b});
    unsigned w; __builtin_memcpy(&w, &t, 4); return w;
}

union FR { bf16x8 v; unsigned short u[8]; unsigned w[4]; };

// One wave (64 threads) per 16-row batch tile. Transposed-z formulation:
// D^T[c_local, r] with gate-col order tile0=[i0,f0,i1,f1,...,i7,f7], tile1=[g0,o0,...].
// Lane l: r = l&15 (batch row), grp = l>>4; acc regs = c_local 4*grp..4*grp+3
// => lane owns full i,f,g,o of units 2*grp, 2*grp+1 for row r. No gather swizzles.
__global__ __launch_bounds__(64)
void lstm_mfma(const float* __restrict__ x,
               const float* __restrict__ kern,
               const float* __restrict__ rk,
               const float* __restrict__ bias,
               const float* __restrict__ w1,
               const float* __restrict__ b1,
               const float* __restrict__ w2,
               const float* __restrict__ b2,
               float* __restrict__ out)
{
    const int l   = threadIdx.x;
    const int r15 = l & 15;
    const int grp = l >> 4;

    // A-fragment row this lane supplies: c_local = l&15; map to real kernel column.
    const int mA = r15 >> 1, bA = r15 & 1;
    const int kc0 = mA + 8 * bA;          // tile0: i_m (b=0) / f_m (b=1)
    const int kc1 = 16 + mA + 8 * bA;     // tile1: g_m / o_m

    FR A0f, A1f, R0f, R1f, hf;
#pragma unroll
    for (int j = 0; j < 8; ++j) {
        const int f = 8 * grp + j;                       // k index this lane supplies
        A0f.u[j] = f2bfu(kern[f * 32 + kc0]);
        A1f.u[j] = f2bfu(kern[f * 32 + kc1]);
        // R^T padded: k rows 8..31 are zero (grp 1..3 lanes supply zeros)
        R0f.u[j] = (grp == 0) ? f2bfu(rk[j * 32 + kc0]) : (unsigned short)0;
        R1f.u[j] = (grp == 0) ? f2bfu(rk[j * 32 + kc1]) : (unsigned short)0;
    }

    f32x4 binit0, binit1;
#pragma unroll
    for (int i = 0; i < 4; ++i) {
        const int cl = 4 * grp + i, mm = cl >> 1, bb = cl & 1;
        binit0[i] = bias[mm + 8 * bb];
        binit1[i] = bias[16 + mm + 8 * bb];
    }

    hf.w[0] = 0; hf.w[1] = 0; hf.w[2] = 0; hf.w[3] = 0;   // h = 0
    float cA = 0.f, cB = 0.f;                             // c for units 2g, 2g+1
    float hv0=0.f,hv1=0.f,hv2=0.f,hv3=0.f,hv4=0.f,hv5=0.f,hv6=0.f,hv7=0.f;

    const size_t row = (size_t)blockIdx.x * 16 + r15;
    const float* xp = x + row * (TSTEPS * FDIM) + grp * 8;   // B-frag: f = 8*grp + j

    auto STEP = [&](const float4& x0, const float4& x1) {
        FR xf;
        xf.w[0] = pk2(x0.x, x0.y);
        xf.w[1] = pk2(x0.z, x0.w);
        xf.w[2] = pk2(x1.x, x1.y);
        xf.w[3] = pk2(x1.z, x1.w);
        f32x4 a0 = __builtin_amdgcn_mfma_f32_16x16x32_bf16(A0f.v, xf.v, binit0, 0, 0, 0);
        f32x4 a1 = __builtin_amdgcn_mfma_f32_16x16x32_bf16(A1f.v, xf.v, binit1, 0, 0, 0);
        a0 = __builtin_amdgcn_mfma_f32_16x16x32_bf16(R0f.v, hf.v, a0, 0, 0, 0);
        a1 = __builtin_amdgcn_mfma_f32_16x16x32_bf16(R1f.v, hf.v, a1, 0, 0, 0);
        // acc0 = [i_A, f_A, i_B, f_B], acc1 = [g_A, o_A, g_B, o_B]  (A=unit 2g, B=2g+1)
        float iA = fmaxf(a0[0], 0.f), fA = fmaxf(a0[1], 0.f);
        float iB = fmaxf(a0[2], 0.f), fB = fmaxf(a0[3], 0.f);
        float gA = fast_tanh(a1[0]), oA = fmaxf(a1[1], 0.f);
        float gB = fast_tanh(a1[2]), oB = fmaxf(a1[3], 0.f);
        cA = fmaf(fA, cA, iA * gA);
        cB = fmaf(fB, cB, iB * gB);
        float hA = oA * fast_tanh(cA);
        float hB = oB * fast_tanh(cB);
        // redistribute: every lane ends with all 8 h of its row, order h_{k ^ 2*grp}
        float t2 = swzf<0x401F>(hA);   // xor 16
        float t3 = swzf<0x401F>(hB);
        float t4 = crossf(hA);         // xor 32
        float t5 = crossf(hB);
        float t6 = crossf(t2);
        float t7 = crossf(t3);
        hf.w[0] = pk2(hA, hB);         // grp0 lanes hold exactly [h0..h7] = B-frag k=0..7
        hf.w[1] = pk2(t2, t3);
        hf.w[2] = pk2(t4, t5);
        hf.w[3] = pk2(t6, t7);
        hv0 = hA; hv1 = hB; hv2 = t2; hv3 = t3; hv4 = t4; hv5 = t5; hv6 = t6; hv7 = t7;
    };

#define LD4(t, o) (*(const float4*)(xp + (size_t)(t) * FDIM + (o)))
    float4 Xa0 = LD4(0, 0), Xa1 = LD4(0, 4);
    float4 Xb0 = LD4(1, 0), Xb1 = LD4(1, 4);

    for (int t = 0; t < TSTEPS - 2; t += 2) {
        float4 Na0 = LD4(t + 2, 0), Na1 = LD4(t + 2, 4);
        float4 Nb0 = LD4(t + 3, 0), Nb1 = LD4(t + 3, 4);
        STEP(Xa0, Xa1);
        STEP(Xb0, Xb1);
        Xa0 = Na0; Xa1 = Na1; Xb0 = Nb0; Xb1 = Nb1;
    }
    STEP(Xa0, Xa1);
    STEP(Xb0, Xb1);
#undef LD4

    // ---- MLP head. hv[k] = h_{k ^ 2*grp} for row r15. Lane computes m-cols grp*16..+15.
    const float hvv[8] = {hv0, hv1, hv2, hv3, hv4, hv5, hv6, hv7};
    const int g2 = 2 * grp;
    float o0 = 0.f, o1 = 0.f, o2 = 0.f, o3 = 0.f;
#pragma unroll
    for (int cc = 0; cc < 16; ++cc) {
        const int col = grp * 16 + cc;
        float s = b1[col];
#pragma unroll
        for (int k = 0; k < 8; ++k)
            s = fmaf(hvv[k], w1[(k ^ g2) * 64 + col], s);
        s = fmaxf(s, 0.f);
        o0 = fmaf(s, w2[col * 4 + 0], o0);
        o1 = fmaf(s, w2[col * 4 + 1], o1);
        o2 = fmaf(s, w2[col * 4 + 2], o2);
        o3 = fmaf(s, w2[col * 4 + 3], o3);
    }
    // reduce the 4 grp-partials per row: xor16 then xor32
    o0 += swzf<0x401F>(o0); o1 += swzf<0x401F>(o1);
    o2 += swzf<0x401F>(o2); o3 += swzf<0x401F>(o3);
    o0 += crossf(o0); o1 += crossf(o1);
    o2 += crossf(o2); o3 += crossf(o3);

    if (l < 16) {
        float4 r;
        r.x = sigmoidf_(o0 + b2[0]);
        r.y = sigmoidf_(o1 + b2[1]);
        r.z = sigmoidf_(o2 + b2[2]);
        r.w = sigmoidf_(o3 + b2[3]);
        *(float4*)&out[((size_t)blockIdx.x * 16 + l) * 4] = r;
    }
}

extern "C" void kernel_launch(void* const* d_in, const int* in_sizes, int n_in,
                              void* d_out, int out_size, void* d_ws, size_t ws_size,
                              hipStream_t stream)
{
    const float* x    = (const float*)d_in[0];
    const float* kern = (const float*)d_in[1];
    const float* rk   = (const float*)d_in[2];
    const float* bias = (const float*)d_in[3];
    const float* w1   = (const float*)d_in[4];
    const float* b1   = (const float*)d_in[5];
    const float* w2   = (const float*)d_in[6];
    const float* b2   = (const float*)d_in[7];

    dim3 grid(4096 / 16);   // 256 one-wave blocks -> 1 wave/CU, chain-latency design
    dim3 block(64);
    lstm_mfma<<<grid, block, 0, stream>>>(x, kern, rk, bias, w1, b1, w2, b2, (float*)d_out);
}